// Round 19
// baseline (9429.308 us; speedup 1.0000x reference)
//
#include <hip/hip_runtime.h>
#include <math.h>

#define NDIMX 2941
#define NQ 1200
#define KB 800
#define KP 720
#define KU 1520
#define NC 400
#define NBT 128
#define NRHS 528
#define GRID 256
#define TPB 256

__device__ __forceinline__ int umap(int x){ return (x < 1200) ? x : x - 720; }

__device__ __forceinline__ const float* qrowp(int rr, const float* Yf, const float* Uf,
                                              const float* Up, const float* Yp){
  if (rr < 480) return Yf + (size_t)rr*NDIMX;
  if (rr < 800) return Uf + (size_t)(rr-480)*NDIMX;
  if (rr < 960) return Up + (size_t)(rr-800)*NDIMX;
  return Yp + (size_t)(rr-960)*NDIMX;
}

// ---------------- device-scope grid barrier (round-5/9 verified protocol) ----------------
__device__ __forceinline__ void gbar(unsigned* cnt, int& id){
  __syncthreads();
  if (threadIdx.x == 0){
    unsigned* c = cnt + id;
    __hip_atomic_fetch_add(c, 1u, __ATOMIC_RELEASE, __HIP_MEMORY_SCOPE_SYSTEM);
    while (__hip_atomic_load(c, __ATOMIC_RELAXED, __HIP_MEMORY_SCOPE_SYSTEM) < (unsigned)GRID){
      __builtin_amdgcn_s_sleep(8);
    }
    (void)__hip_atomic_load(c, __ATOMIC_ACQUIRE, __HIP_MEMORY_SCOPE_AGENT);
  }
  __syncthreads();
  id++;
}

// XCD-aware bijective tile range (m204) — Gram only
__device__ __forceinline__ void swz(int T, int& t0, int& tend){
  int x = blockIdx.x & 7, y = blockIdx.x >> 3;
  int q = T >> 3, r = T & 7;
  int nx = q + (x < r ? 1 : 0);
  int base = (x < r) ? x*(q+1) : r*(q+1) + (x-r)*q;
  t0 = base + y; tend = base + nx;
}

// ---------------- Gram stage (r18-verified) ----------------
__device__ void st_gram(const float* Yf, const float* Uf, const float* Up, const float* Yp,
                        float* G, float* shf){
  float* At = shf;            // [32][68]
  float* Bt = shf + 32*68;    // [32][68]
  const int ntri = 190;
  int tid = threadIdx.x, tx = tid%16, ty = tid/16;
  int t0, tend; swz(ntri, t0, tend);
  for (int t = t0; t < tend; t += 32){
    int rem = t, ti = 0;
    while (rem >= ti+1){ rem -= ti+1; ++ti; }
    int tj = rem;
    int i0 = ti*64, j0 = tj*64;
    float acc[4][4] = {};
    for (int k0 = 0; k0 < NDIMX; k0 += 32){
      for (int l = tid; l < 2048; l += TPB){
        int r2 = l >> 5, k = l & 31;
        int gr = i0 + r2, gk = k0 + k;
        At[k*68 + r2] = (gr < NQ && gk < NDIMX) ? qrowp(gr,Yf,Uf,Up,Yp)[gk] : 0.f;
      }
      if (ti != tj){
        for (int l = tid; l < 2048; l += TPB){
          int r2 = l >> 5, k = l & 31;
          int gr = j0 + r2, gk = k0 + k;
          Bt[k*68 + r2] = (gr < NQ && gk < NDIMX) ? qrowp(gr,Yf,Uf,Up,Yp)[gk] : 0.f;
        }
      }
      __syncthreads();
      float* Bp = (ti==tj) ? At : Bt;
      #pragma unroll 8
      for (int kk=0; kk<32; ++kk){
        float4 av = *(const float4*)&At[kk*68 + ty*4];
        float4 bv = *(const float4*)&Bp[kk*68 + tx*4];
        float a0=av.x,a1=av.y,a2=av.z,a3=av.w;
        float b0=bv.x,b1=bv.y,b2=bv.z,b3=bv.w;
        acc[0][0]+=a0*b0; acc[0][1]+=a0*b1; acc[0][2]+=a0*b2; acc[0][3]+=a0*b3;
        acc[1][0]+=a1*b0; acc[1][1]+=a1*b1; acc[1][2]+=a1*b2; acc[1][3]+=a1*b3;
        acc[2][0]+=a2*b0; acc[2][1]+=a2*b1; acc[2][2]+=a2*b2; acc[2][3]+=a2*b3;
        acc[3][0]+=a3*b0; acc[3][1]+=a3*b1; acc[3][2]+=a3*b2; acc[3][3]+=a3*b3;
      }
      __syncthreads();
    }
    for (int i=0;i<4;i++) for (int j=0;j<4;j++){
      int gi = i0 + ty*4 + i, gj = j0 + tx*4 + j;
      if (gi < NQ && gj < NQ){
        G[(size_t)gi*NQ+gj] = acc[i][j];
        G[(size_t)gj*NQ+gi] = acc[i][j];
      }
    }
  }
}

// ---------------- fused elementwise assembly (r17-verified) ----------------
__device__ void st_assemble(const float* G, const float* q, const float* r, double isg,
    const float* yref, const float* uref, const float* u_ini, const float* y_ini,
    float* M11, float* T12, float* R1, float* dM, float* rhs2){
  int tid0 = blockIdx.x*TPB + threadIdx.x, stride = gridDim.x*TPB;
  for (int idx=tid0; idx<KB*KB; idx+=stride){
    int i=idx/KB, j=idx-i*KB;
    double v = (double)G[(size_t)i*NQ+j]*isg;
    if (i==j){ double w=(i<480)?(double)q[i%12]:(double)r[(i-480)%8]; v += 0.5/w; }
    M11[idx]=(float)v;
  }
  for (int idx=tid0; idx<KB*KP; idx+=stride){
    int i=idx/KP, j=idx-i*KP;
    int pc=(j<400)?(800+j):(80+j);
    T12[idx]=(float)((double)G[(size_t)i*NQ+pc]*isg);
  }
  for (int idx=tid0; idx<KU*NC; idx+=stride){
    int i=idx/NC, j=idx-i*NC;
    R1[(size_t)i*NRHS+j]=G[(size_t)umap(i)*NQ+800+j];
  }
  for (int idx=tid0; idx<KB*NBT; idx+=stride){
    int k=idx/NBT, t=idx-k*NBT;
    double v=(k<480)? 2.0*(double)q[k%12]*(double)yref[(size_t)t*480+k]
                    : 2.0*(double)r[(k-480)%8]*(double)uref[(size_t)t*320+(k-480)];
    dM[idx]=(float)v;
  }
  for (int idx=tid0; idx<NC*NBT; idx+=stride){
    int j=idx/NBT, t=idx-j*NBT;
    rhs2[idx]= -((j<160)?u_ini[(size_t)t*160+j]:y_ini[(size_t)t*240+(j-160)]);
  }
}

// ---------------- multi-GEMM job executor: ping-pong LDS, 1 sync/chunk, 2-deep loads ----
struct Job {
  const float* A; const float* B; const float* Cin; float* Cout;
  int lda, ldb, ldcin, ldc, M, N, K, transa, mapa;
  double alpha, beta;
};

__device__ void run_tile(const Job& jb, int t, float* stage){
  float* As0 = stage;          // [16][68]
  float* Bs0 = stage + 1088;
  float* As1 = stage + 2176;
  float* Bs1 = stage + 3264;
  int tid = threadIdx.x, tx = tid%16, ty = tid/16;
  const float* A = jb.A; const float* B = jb.B;
  int lda = jb.lda, ldb = jb.ldb, M = jb.M, N = jb.N, K = jb.K;
  int transa = jb.transa, mapa = jb.mapa;
  int ntn = (N+63)>>6;
  int m0 = (t/ntn)*64, n0 = (t - (t/ntn)*ntn)*64;
  double acc[4][4] = {};
  float ra[4], rb[4];
  auto loadAB = [&](int k0v){
    #pragma unroll
    for (int s=0;s<4;s++){
      int l = tid + s*TPB;
      float v = 0.f;
      if (transa == 0){
        int m = l>>4, k = l&15;
        int gm = m0+m, gk = k0v+k;
        if (gm<M && gk<K){ int row = mapa ? umap(gm) : gm; v = A[(size_t)row*lda + gk]; }
      } else {
        int k = l>>6, m = l&63;
        int gm = m0+m, gk = k0v+k;
        if (gm<M && gk<K){ int row = mapa ? umap(gk) : gk; v = A[(size_t)row*lda + gm]; }
      }
      ra[s] = v;
      int kb = l>>6, n = l&63;
      int gn = n0+n, gkb = k0v+kb;
      rb[s] = (gn<N && gkb<K) ? B[(size_t)gkb*ldb + gn] : 0.f;
    }
  };
  auto storeAB = [&](float* Aw, float* Bw){
    #pragma unroll
    for (int s=0;s<4;s++){
      int l = tid + s*TPB;
      if (transa == 0){ int m=l>>4, k=l&15; Aw[k*68+m] = ra[s]; }
      else            { int k=l>>6, m=l&63; Aw[k*68+m] = ra[s]; }
      int kb=l>>6, n=l&63; Bw[kb*68+n] = rb[s];
    }
  };
  loadAB(0);
  storeAB(As0, Bs0);
  loadAB(16);
  __syncthreads();
  for (int k0 = 0; k0 < K; k0 += 16){
    int p = (k0>>4)&1;
    const float* Ar = p ? As1 : As0;
    const float* Br = p ? Bs1 : Bs0;
    if (k0+16 < K){
      storeAB(p ? As0 : As1, p ? Bs0 : Bs1);
      loadAB(k0+32);
    }
    #pragma unroll
    for (int kk=0; kk<16; ++kk){
      float4 av = *(const float4*)&Ar[kk*68 + ty*4];
      float4 bv = *(const float4*)&Br[kk*68 + tx*4];
      double a0=av.x, a1=av.y, a2=av.z, a3=av.w;
      double b0=bv.x, b1=bv.y, b2=bv.z, b3=bv.w;
      acc[0][0]+=a0*b0; acc[0][1]+=a0*b1; acc[0][2]+=a0*b2; acc[0][3]+=a0*b3;
      acc[1][0]+=a1*b0; acc[1][1]+=a1*b1; acc[1][2]+=a1*b2; acc[1][3]+=a1*b3;
      acc[2][0]+=a2*b0; acc[2][1]+=a2*b1; acc[2][2]+=a2*b2; acc[2][3]+=a2*b3;
      acc[3][0]+=a3*b0; acc[3][1]+=a3*b1; acc[3][2]+=a3*b2; acc[3][3]+=a3*b3;
    }
    __syncthreads();
  }
  for (int i=0;i<4;i++) for (int j=0;j<4;j++){
    int gm = m0 + ty*4 + i, gn = n0 + tx*4 + j;
    if (gm < M && gn < N){
      double v = jb.alpha*acc[i][j];
      if (jb.beta != 0.0) v += jb.beta*(double)jb.Cin[(size_t)gm*jb.ldcin + gn];
      jb.Cout[(size_t)gm*jb.ldc + gn] = (float)v;
    }
  }
}

__device__ void run_jobs(const Job* jobs, int njobs, float* stage){
  int cum[5]; int tot = 0;
  for (int j=0;j<njobs;j++){
    cum[j] = tot;
    tot += ((jobs[j].M+63)>>6) * ((jobs[j].N+63)>>6);
  }
  cum[njobs] = tot;
  for (int t = blockIdx.x; t < tot; t += GRID){
    int j = 0;
    while (j+1 < njobs && t >= cum[j+1]) j++;
    run_tile(jobs[j], t - cum[j], stage);
  }
}

// ---------------- Gauss-Jordan, ping-pong, 1 barrier/panel ----------------
// Pivot inverse in f32 (r12-verified numerics), LDS ping-pong: 1 sync/iteration.
// bs in {64,32,16} (even) -> result always lands back in TPa.
__device__ float* gj_pivinv_lds(const float* A, int lda, int n, int k0,
                                float* TPa, float* TPb){
  int bs = n - k0; if (bs > 64) bs = 64;
  int tid = threadIdx.x;
  for (int l = tid; l < bs*bs; l += TPB){
    int i=l/bs, j=l-i*bs;
    TPa[i*68+j] = A[(size_t)(k0+i)*lda + k0+j];
  }
  __syncthreads();
  float* cur = TPa; float* nxt = TPb;
  for (int k=0;k<bs;k++){
    float dd = 1.0f/cur[k*68+k];
    for (int l = tid; l < bs*bs; l += TPB){
      int i=l/bs, j=l-i*bs;
      float ck = cur[i*68+k];
      float rk = (j==k) ? dd : cur[k*68+j]*dd;
      float v;
      if (i==k) v = rk;
      else if (j==k) v = -ck*dd;
      else v = cur[i*68+j] - ck*rk;
      nxt[i*68+j] = v;
    }
    __syncthreads();
    float* tp = cur; cur = nxt; nxt = tp;
  }
  return cur;
}

// Phase B (r9/r13-verified math; ping-pong stage, 1 sync/chunk)
__device__ void gj_phaseB(const float* Ac, float* An, int lda, int n, int k0,
                          const float* TPf, float* Pn, float* stage){
  int bs = n - k0; if (bs > 64) bs = 64;
  int nout = n - bs;
  int ntc = (n+63)>>6, ntm = (nout+63)>>6;
  float* S0 = stage;          // [16][68]
  float* S1 = stage + 1088;
  float* S2 = stage + 2176;
  float* S3 = stage + 3264;
  int tid = threadIdx.x, tx = tid%16, ty = tid/16;
  int T = ntm*ntc;
  for (int t = blockIdx.x; t < T; t += GRID){
    int mi = t / ntc, ci = t - mi*ntc;
    int m0 = mi*64, j0 = ci*64;
    // ---- step 1: Pn = TPf @ PR(cols); pivot cols get TPf ----
    float rbv[4];
    auto loadB1 = [&](int kpv){
      #pragma unroll
      for (int s=0;s<4;s++){
        int l = tid + s*TPB;
        int k=l>>6, j=l&63;
        rbv[s] = (kpv+k<bs && j0+j<n) ? Ac[(size_t)(k0+kpv+k)*lda + j0+j] : 0.f;
      }
    };
    auto storeB1 = [&](float* Bw){
      #pragma unroll
      for (int s=0;s<4;s++){
        int l = tid + s*TPB;
        int k=l>>6, j=l&63;
        Bw[k*68+j] = rbv[s];
      }
    };
    double acc[4][4] = {};
    loadB1(0); storeB1(S0); loadB1(16);
    __syncthreads();
    for (int kp=0; kp<bs; kp+=16){
      int p = (kp>>4)&1;
      const float* Br = p ? S1 : S0;
      if (kp+16 < bs){ storeB1(p ? S0 : S1); loadB1(kp+32); }
      #pragma unroll
      for (int kk=0; kk<16; ++kk){
        double a0=(ty*4+0<bs)?(double)TPf[(ty*4+0)*68 + kp+kk]:0.0;
        double a1=(ty*4+1<bs)?(double)TPf[(ty*4+1)*68 + kp+kk]:0.0;
        double a2=(ty*4+2<bs)?(double)TPf[(ty*4+2)*68 + kp+kk]:0.0;
        double a3=(ty*4+3<bs)?(double)TPf[(ty*4+3)*68 + kp+kk]:0.0;
        float4 bv = *(const float4*)&Br[kk*68 + tx*4];
        double b0=bv.x, b1=bv.y, b2=bv.z, b3=bv.w;
        acc[0][0]+=a0*b0; acc[0][1]+=a0*b1; acc[0][2]+=a0*b2; acc[0][3]+=a0*b3;
        acc[1][0]+=a1*b0; acc[1][1]+=a1*b1; acc[1][2]+=a1*b2; acc[1][3]+=a1*b3;
        acc[2][0]+=a2*b0; acc[2][1]+=a2*b1; acc[2][2]+=a2*b2; acc[2][3]+=a2*b3;
        acc[3][0]+=a3*b0; acc[3][1]+=a3*b1; acc[3][2]+=a3*b2; acc[3][3]+=a3*b3;
      }
      __syncthreads();
    }
    for (int i=0;i<4;i++) for (int j=0;j<4;j++){
      int li = ty*4+i, lj = tx*4+j;
      int gj = j0 + lj;
      if (li < bs){
        double v = acc[i][j];
        if (gj >= k0 && gj < k0+bs) v = TPf[li*68 + (gj-k0)];
        Pn[li*68+lj] = (float)v;
      }
    }
    __syncthreads();
    // ---- step 2: panel-row write duty ----
    if (mi == 0){
      for (int l = tid; l < bs*64; l += TPB){
        int i2 = l>>6, j2 = l&63;
        int gj = j0 + j2;
        if (gj < n) An[(size_t)(k0+i2)*lda + gj] = Pn[i2*68+j2];
      }
    }
    // ---- step 3: outside rows: An = Ac - pivcol(Ac) @ Pn ----
    float rav[4];
    auto loadA3 = [&](int kpv){
      #pragma unroll
      for (int s=0;s<4;s++){
        int l = tid + s*TPB;
        int k=l>>6, m=l&63;
        int gm = m0+m;
        float v = 0.f;
        if (kpv+k<bs && gm<nout){
          int gi = (gm < k0) ? gm : gm + bs;
          v = Ac[(size_t)gi*lda + k0 + kpv + k];
        }
        rav[s] = v;
      }
    };
    auto storeA3 = [&](float* Aw){
      #pragma unroll
      for (int s=0;s<4;s++){
        int l = tid + s*TPB;
        int k=l>>6, m=l&63;
        Aw[k*68+m] = rav[s];
      }
    };
    double acc2[4][4] = {};
    loadA3(0); storeA3(S2); loadA3(16);
    __syncthreads();
    for (int kp=0; kp<bs; kp+=16){
      int p = (kp>>4)&1;
      const float* Ar = p ? S3 : S2;
      if (kp+16 < bs){ storeA3(p ? S2 : S3); loadA3(kp+32); }
      #pragma unroll
      for (int kk=0; kk<16; ++kk){
        float4 av = *(const float4*)&Ar[kk*68 + ty*4];
        float4 bv = *(const float4*)&Pn[(kp+kk)*68 + tx*4];
        double a0=av.x, a1=av.y, a2=av.z, a3=av.w;
        double b0=bv.x, b1=bv.y, b2=bv.z, b3=bv.w;
        acc2[0][0]+=a0*b0; acc2[0][1]+=a0*b1; acc2[0][2]+=a0*b2; acc2[0][3]+=a0*b3;
        acc2[1][0]+=a1*b0; acc2[1][1]+=a1*b1; acc2[1][2]+=a1*b2; acc2[1][3]+=a1*b3;
        acc2[2][0]+=a2*b0; acc2[2][1]+=a2*b1; acc2[2][2]+=a2*b2; acc2[2][3]+=a2*b3;
        acc2[3][0]+=a3*b0; acc2[3][1]+=a3*b1; acc2[3][2]+=a3*b2; acc2[3][3]+=a3*b3;
      }
      __syncthreads();
    }
    for (int i=0;i<4;i++) for (int j=0;j<4;j++){
      int gm = m0 + ty*4 + i, gj = j0 + tx*4 + j;
      if (gm < nout && gj < n){
        int gi = (gm < k0) ? gm : gm + bs;
        double base = (gj >= k0 && gj < k0+bs) ? 0.0 : (double)Ac[(size_t)gi*lda + gj];
        An[(size_t)gi*lda + gj] = (float)(base - acc2[i][j]);
      }
    }
    __syncthreads();
  }
}

__device__ float* gj_inv(float* A, float* B, int n, float* TPa, float* TPb,
                         float* Pn, float* stage, unsigned* cnt, int& bid){
  float* cur = A; float* nxt = B;
  for (int k0 = 0; k0 < n; k0 += 64){
    float* TPf = gj_pivinv_lds(cur, n, n, k0, TPa, TPb);
    gj_phaseB(cur, nxt, n, n, k0, TPf, Pn, stage);
    gbar(cnt, bid);
    float* tmp = cur; cur = nxt; nxt = tmp;
  }
  return cur;
}

// ---------------- misc stages ----------------
__device__ void st_copy(const float* s, float* d, size_t n){
  for (size_t i = (size_t)blockIdx.x*TPB + threadIdx.x; i < n; i += (size_t)gridDim.x*TPB)
    d[i] = s[i];
}

__device__ void st_out(const float* Bg, float* out){
  int stride = gridDim.x*TPB;
  for (int idx = blockIdx.x*TPB + threadIdx.x; idx < 128*800; idx += stride){
    if (idx < 128*320){
      int t = idx/320, i = idx-(idx/320)*320;
      out[idx] = Bg[(size_t)(480+i)*NBT + t];
    } else {
      int l = idx - 128*320;
      int t = l/480, i = l-(l/480)*480;
      out[idx] = Bg[(size_t)i*NBT + t];
    }
  }
}

__global__ __launch_bounds__(256) void k_init(unsigned* cnt){
  int i = blockIdx.x*256 + threadIdx.x;
  if (i < 1024) cnt[i] = 0;
}

// ---------------- mega kernel ----------------
__global__ __launch_bounds__(256) void k_mega(
    const float* Up, const float* Yp, const float* Uf, const float* Yf,
    const float* q, const float* r, const float* lam,
    const float* yref, const float* uref, const float* u_ini, const float* y_ini,
    float* out,
    float* Gram, float* M11, float* T12, float* G1, float* SP, float* R1,
    float* U1, float* X2b, float* Sm, float* dM, float* rhs2, float* tAc,
    float* P1, float* BUZ, float* EXT, unsigned* cnt){
  // LDS map (floats, base 16B-aligned):
  //   TPa [64][68] : 0     .. 4352
  //   TPb [64][68] : 4352  .. 8704
  //   Pn  [64][68] : 8704  .. 13056
  //   stage 4x[16][68] : 13056 .. 17408
  // st_gram uses shf front (2x[32][68] = 4352) inside TPa.
  __shared__ __align__(16) float shf[17408];
  float* TPa  = shf;
  float* TPb  = shf + 4352;
  float* Pn   = shf + 8704;
  float* stage= shf + 13056;
  int bid = 0;
  double sg = 2.0*(double)lam[0];
  double isg = 1.0/sg, isg2 = isg*isg;

  st_gram(Yf, Uf, Up, Yp, Gram, shf);
  gbar(cnt, bid);
  st_assemble(Gram, q, r, isg, yref, uref, u_ini, y_ini, EXT, T12, R1, dM, rhs2);
  gbar(cnt, bid);
  { // {3,14,17}
    Job js[3] = {
      {Gram, dM, R1+NC, R1+NC, NQ, NBT, NRHS, NRHS, KU, NBT, KB, 0, 1, 1.0, 0.0},
      {Gram+(size_t)800*NQ, dM, rhs2, tAc, NQ, NBT, NBT, NBT, NC, NBT, KB, 0, 0, isg, 1.0},
      {Gram, dM, P1, P1, NQ, NBT, NBT, NBT, KB, NBT, KB, 0, 0, isg, 0.0},
    };
    run_jobs(js, 3, stage);
  }
  gbar(cnt, bid);
  float* M11f = gj_inv(EXT, M11, KB, TPa, TPb, Pn, stage, cnt, bid);   // 13 barriers
  { // {5,8}
    Job js[2] = {
      {M11f, T12, G1, G1, KB, KP, KP, KP, KB, KP, KB, 0, 0, 1.0, 0.0},
      {M11f, R1, U1, U1, KB, NRHS, NRHS, NRHS, KB, NRHS, KB, 0, 0, 1.0, 0.0},
    };
    run_jobs(js, 2, stage);
  }
  gbar(cnt, bid);
  { // {6,9}
    Job js[2] = {
      {T12, G1, SP, SP, KP, KP, KP, KP, KP, KP, KB, 1, 0, 1.0, 0.0},
      {T12, U1, R1+(size_t)KB*NRHS, R1+(size_t)KB*NRHS, KP, NRHS, NRHS, NRHS, KP, NRHS, KB, 1, 0, 1.0, -1.0},
    };
    run_jobs(js, 2, stage);
  }
  gbar(cnt, bid);
  float* SPf = gj_inv(SP, EXT, KP, TPa, TPb, Pn, stage, cnt, bid);     // 12 barriers
  { // X2 = SPi @ V
    Job js[1] = {
      {SPf, R1+(size_t)KB*NRHS, X2b, X2b, KP, NRHS, NRHS, NRHS, KP, NRHS, KP, 0, 0, 1.0, 0.0},
    };
    run_jobs(js, 1, stage);
  }
  gbar(cnt, bid);
  { // {11}
    st_copy(X2b, R1+(size_t)KB*NRHS, (size_t)KP*NRHS);
    Job js[1] = {
      {G1, X2b, U1, R1, KP, NRHS, NRHS, NRHS, KB, NRHS, KP, 0, 0, -1.0, 1.0},
    };
    run_jobs(js, 1, stage);
  }
  gbar(cnt, bid);
  { // {12,15,19,20}
    Job js[4] = {
      {Gram+800, R1, Gram+(size_t)800*NQ+800, EXT, NQ, NRHS, NQ, NC, NC, NC, KU, 1, 1, -isg2, isg},
      {Gram+800, R1+NC, tAc, rhs2, NQ, NRHS, NBT, NBT, NC, NBT, KU, 1, 1, -isg2, 1.0},
      {Gram, R1+NC, P1, P1, NQ, NRHS, NBT, NBT, KB, NBT, KU, 1, 1, -isg2, 1.0},
      {Gram, R1, BUZ, BUZ, NQ, NRHS, NC, NC, KB, NC, KU, 1, 1, 1.0, 0.0},
    };
    run_jobs(js, 4, stage);
  }
  gbar(cnt, bid);
  float* Smf = gj_inv(EXT, Sm, NC, TPa, TPb, Pn, stage, cnt, bid);     // 7 barriers
  { // nu = Smi @ rhs2
    Job js[1] = {
      {Smf, rhs2, tAc, tAc, NC, NBT, NBT, NBT, NC, NBT, NC, 0, 0, 1.0, 0.0},
    };
    run_jobs(js, 1, stage);
  }
  gbar(cnt, bid);
  { // {18}
    Job js[1] = {
      {Gram+800, tAc, P1, P1, NQ, NBT, NBT, NBT, KB, NBT, NC, 0, 0, -isg, 1.0},
    };
    run_jobs(js, 1, stage);
  }
  gbar(cnt, bid);
  { // {21}
    Job js[1] = {
      {BUZ, tAc, P1, P1, NC, NBT, NBT, NBT, KB, NBT, NC, 0, 0, isg2, 1.0},
    };
    run_jobs(js, 1, stage);
  }
  gbar(cnt, bid);
  st_out(P1, out);
}

extern "C" void kernel_launch(void* const* d_in, const int* in_sizes, int n_in,
                              void* d_out, int out_size, void* d_ws, size_t ws_size,
                              hipStream_t stream){
  const float* Up   = (const float*)d_in[0];
  const float* Yp   = (const float*)d_in[1];
  const float* Uf   = (const float*)d_in[2];
  const float* Yf   = (const float*)d_in[3];
  // d_in[4] = IPI : unused (projector handled analytically)
  const float* q    = (const float*)d_in[5];
  const float* r    = (const float*)d_in[6];
  const float* lam  = (const float*)d_in[7];
  const float* yref = (const float*)d_in[8];
  const float* uref = (const float*)d_in[9];
  const float* u_ini= (const float*)d_in[10];
  const float* y_ini= (const float*)d_in[11];
  float* out = (float*)d_out;

  float* W = (float*)d_ws;
  size_t o = 0;
  float* Gram = W + o; o += (size_t)NQ*NQ;
  float* M11  = W + o; o += (size_t)KB*KB;
  float* T12  = W + o; o += (size_t)KB*KP;
  float* G1   = W + o; o += (size_t)KB*KP;
  float* SP   = W + o; o += (size_t)KP*KP;
  float* R1   = W + o; o += (size_t)KU*NRHS;
  float* U1   = W + o; o += (size_t)KB*NRHS;
  float* X2b  = W + o; o += (size_t)KP*NRHS;
  float* Sm   = W + o; o += (size_t)NC*NC;
  float* dM   = W + o; o += (size_t)KB*NBT;
  float* rhs2 = W + o; o += (size_t)NC*NBT;
  float* tAc  = W + o; o += (size_t)NC*NBT;
  float* P1   = W + o; o += (size_t)KB*NBT;
  float* BUZ  = W + o; o += (size_t)KB*NC;
  float* EXT  = W + o; o += (size_t)KB*KB;
  unsigned* cnt = (unsigned*)(W + o); o += 512;
  if (ws_size < o*sizeof(float)) return;

  k_init<<<4,256,0,stream>>>(cnt);
  k_mega<<<GRID,TPB,0,stream>>>(Up,Yp,Uf,Yf,q,r,lam,yref,uref,u_ini,y_ini,out,
      Gram,M11,T12,G1,SP,R1,U1,X2b,Sm,dM,rhs2,tAc,P1,BUZ,EXT,cnt);
}

// Round 21
// 8898.767 us; speedup vs baseline: 1.0596x; 1.0596x over previous
//
#include <hip/hip_runtime.h>
#include <math.h>

#define NDIMX 2941
#define NQ 1200
#define KB 800
#define KP 720
#define KU 1520
#define NC 400
#define NBT 128
#define NRHS 528
#define GRID 256
#define TPB 256

__device__ __forceinline__ int umap(int x){ return (x < 1200) ? x : x - 720; }

__device__ __forceinline__ const float* qrowp(int rr, const float* Yf, const float* Uf,
                                              const float* Up, const float* Yp){
  if (rr < 480) return Yf + (size_t)rr*NDIMX;
  if (rr < 800) return Uf + (size_t)(rr-480)*NDIMX;
  if (rr < 960) return Up + (size_t)(rr-800)*NDIMX;
  return Yp + (size_t)(rr-960)*NDIMX;
}

// ---------------- device-scope grid barrier (round-5/9 verified protocol) ----------------
__device__ __forceinline__ void gbar(unsigned* cnt, int& id){
  __syncthreads();
  if (threadIdx.x == 0){
    unsigned* c = cnt + id;
    __hip_atomic_fetch_add(c, 1u, __ATOMIC_RELEASE, __HIP_MEMORY_SCOPE_SYSTEM);
    while (__hip_atomic_load(c, __ATOMIC_RELAXED, __HIP_MEMORY_SCOPE_SYSTEM) < (unsigned)GRID){
      __builtin_amdgcn_s_sleep(8);
    }
    (void)__hip_atomic_load(c, __ATOMIC_ACQUIRE, __HIP_MEMORY_SCOPE_AGENT);
  }
  __syncthreads();
  id++;
}

// XCD-aware bijective tile range (m204) — Gram only
__device__ __forceinline__ void swz(int T, int& t0, int& tend){
  int x = blockIdx.x & 7, y = blockIdx.x >> 3;
  int q = T >> 3, r = T & 7;
  int nx = q + (x < r ? 1 : 0);
  int base = (x < r) ? x*(q+1) : r*(q+1) + (x-r)*q;
  t0 = base + y; tend = base + nx;
}

// ---------------- Gram stage (f32 acc/store; float4 LDS reads, stride 68) ----------------
__device__ void st_gram(const float* Yf, const float* Uf, const float* Up, const float* Yp,
                        float* G, float* shf){
  float* At = shf;            // [32][68]
  float* Bt = shf + 32*68;    // [32][68]
  const int ntri = 190;
  int tid = threadIdx.x, tx = tid%16, ty = tid/16;
  int t0, tend; swz(ntri, t0, tend);
  for (int t = t0; t < tend; t += 32){
    int rem = t, ti = 0;
    while (rem >= ti+1){ rem -= ti+1; ++ti; }
    int tj = rem;
    int i0 = ti*64, j0 = tj*64;
    float acc[4][4] = {};
    for (int k0 = 0; k0 < NDIMX; k0 += 32){
      for (int l = tid; l < 2048; l += TPB){
        int r2 = l >> 5, k = l & 31;
        int gr = i0 + r2, gk = k0 + k;
        At[k*68 + r2] = (gr < NQ && gk < NDIMX) ? qrowp(gr,Yf,Uf,Up,Yp)[gk] : 0.f;
      }
      if (ti != tj){
        for (int l = tid; l < 2048; l += TPB){
          int r2 = l >> 5, k = l & 31;
          int gr = j0 + r2, gk = k0 + k;
          Bt[k*68 + r2] = (gr < NQ && gk < NDIMX) ? qrowp(gr,Yf,Uf,Up,Yp)[gk] : 0.f;
        }
      }
      __syncthreads();
      float* Bp = (ti==tj) ? At : Bt;
      #pragma unroll 8
      for (int kk=0; kk<32; ++kk){
        float4 av = *(const float4*)&At[kk*68 + ty*4];
        float4 bv = *(const float4*)&Bp[kk*68 + tx*4];
        float a0=av.x,a1=av.y,a2=av.z,a3=av.w;
        float b0=bv.x,b1=bv.y,b2=bv.z,b3=bv.w;
        acc[0][0]+=a0*b0; acc[0][1]+=a0*b1; acc[0][2]+=a0*b2; acc[0][3]+=a0*b3;
        acc[1][0]+=a1*b0; acc[1][1]+=a1*b1; acc[1][2]+=a1*b2; acc[1][3]+=a1*b3;
        acc[2][0]+=a2*b0; acc[2][1]+=a2*b1; acc[2][2]+=a2*b2; acc[2][3]+=a2*b3;
        acc[3][0]+=a3*b0; acc[3][1]+=a3*b1; acc[3][2]+=a3*b2; acc[3][3]+=a3*b3;
      }
      __syncthreads();
    }
    for (int i=0;i<4;i++) for (int j=0;j<4;j++){
      int gi = i0 + ty*4 + i, gj = j0 + tx*4 + j;
      if (gi < NQ && gj < NQ){
        G[(size_t)gi*NQ+gj] = acc[i][j];
        G[(size_t)gj*NQ+gi] = acc[i][j];
      }
    }
  }
}

// ---------------- fused elementwise assembly (f32 store) ----------------
__device__ void st_assemble(const float* G, const float* q, const float* r, double isg,
    const float* yref, const float* uref, const float* u_ini, const float* y_ini,
    float* M11, float* T12, float* R1, float* dM, float* rhs2){
  int tid0 = blockIdx.x*TPB + threadIdx.x, stride = gridDim.x*TPB;
  for (int idx=tid0; idx<KB*KB; idx+=stride){
    int i=idx/KB, j=idx-i*KB;
    double v = (double)G[(size_t)i*NQ+j]*isg;
    if (i==j){ double w=(i<480)?(double)q[i%12]:(double)r[(i-480)%8]; v += 0.5/w; }
    M11[idx]=(float)v;
  }
  for (int idx=tid0; idx<KB*KP; idx+=stride){
    int i=idx/KP, j=idx-i*KP;
    int pc=(j<400)?(800+j):(80+j);
    T12[idx]=(float)((double)G[(size_t)i*NQ+pc]*isg);
  }
  for (int idx=tid0; idx<KU*NC; idx+=stride){
    int i=idx/NC, j=idx-i*NC;
    R1[(size_t)i*NRHS+j]=G[(size_t)umap(i)*NQ+800+j];
  }
  for (int idx=tid0; idx<KB*NBT; idx+=stride){
    int k=idx/NBT, t=idx-k*NBT;
    double v=(k<480)? 2.0*(double)q[k%12]*(double)yref[(size_t)t*480+k]
                    : 2.0*(double)r[(k-480)%8]*(double)uref[(size_t)t*320+(k-480)];
    dM[idx]=(float)v;
  }
  for (int idx=tid0; idx<NC*NBT; idx+=stride){
    int j=idx/NBT, t=idx-j*NBT;
    rhs2[idx]= -((j<160)?u_ini[(size_t)t*160+j]:y_ini[(size_t)t*240+(j-160)]);
  }
}

// ---------------- multi-GEMM job executor (float4 LDS reads, stride 68) --------
struct Job {
  const float* A; const float* B; const float* Cin; float* Cout;
  int lda, ldb, ldcin, ldc, M, N, K, transa, mapa;
  double alpha, beta;
};

__device__ void run_tile(const Job& jb, int t, float* stage){
  float* As = stage;          // [16][68]
  float* Bs = stage + 1088;   // [16][68]
  int tid = threadIdx.x, tx = tid%16, ty = tid/16;
  const float* A = jb.A; const float* B = jb.B;
  int lda = jb.lda, ldb = jb.ldb, M = jb.M, N = jb.N, K = jb.K;
  int transa = jb.transa, mapa = jb.mapa;
  int ntn = (N+63)>>6;
  int m0 = (t/ntn)*64, n0 = (t - (t/ntn)*ntn)*64;
  double acc[4][4] = {};
  float ra[4], rb[4];
  auto loadAB = [&](int k0v){
    #pragma unroll
    for (int s=0;s<4;s++){
      int l = tid + s*TPB;
      float v = 0.f;
      if (transa == 0){
        int m = l>>4, k = l&15;
        int gm = m0+m, gk = k0v+k;
        if (gm<M && gk<K){ int row = mapa ? umap(gm) : gm; v = A[(size_t)row*lda + gk]; }
      } else {
        int k = l>>6, m = l&63;
        int gm = m0+m, gk = k0v+k;
        if (gm<M && gk<K){ int row = mapa ? umap(gk) : gk; v = A[(size_t)row*lda + gm]; }
      }
      ra[s] = v;
      int kb = l>>6, n = l&63;
      int gn = n0+n, gkb = k0v+kb;
      rb[s] = (gn<N && gkb<K) ? B[(size_t)gkb*ldb + gn] : 0.f;
    }
  };
  loadAB(0);
  for (int k0 = 0; k0 < K; k0 += 16){
    __syncthreads();
    #pragma unroll
    for (int s=0;s<4;s++){
      int l = tid + s*TPB;
      if (transa == 0){ int m=l>>4, k=l&15; As[k*68+m] = ra[s]; }
      else            { int k=l>>6, m=l&63; As[k*68+m] = ra[s]; }
      int kb=l>>6, n=l&63; Bs[kb*68+n] = rb[s];
    }
    __syncthreads();
    if (k0+16 < K) loadAB(k0+16);
    #pragma unroll
    for (int kk=0; kk<16; ++kk){
      float4 av = *(const float4*)&As[kk*68 + ty*4];
      float4 bv = *(const float4*)&Bs[kk*68 + tx*4];
      double a0=av.x, a1=av.y, a2=av.z, a3=av.w;
      double b0=bv.x, b1=bv.y, b2=bv.z, b3=bv.w;
      acc[0][0]+=a0*b0; acc[0][1]+=a0*b1; acc[0][2]+=a0*b2; acc[0][3]+=a0*b3;
      acc[1][0]+=a1*b0; acc[1][1]+=a1*b1; acc[1][2]+=a1*b2; acc[1][3]+=a1*b3;
      acc[2][0]+=a2*b0; acc[2][1]+=a2*b1; acc[2][2]+=a2*b2; acc[2][3]+=a2*b3;
      acc[3][0]+=a3*b0; acc[3][1]+=a3*b1; acc[3][2]+=a3*b2; acc[3][3]+=a3*b3;
    }
    __syncthreads();
  }
  for (int i=0;i<4;i++) for (int j=0;j<4;j++){
    int gm = m0 + ty*4 + i, gn = n0 + tx*4 + j;
    if (gm < M && gn < N){
      double v = jb.alpha*acc[i][j];
      if (jb.beta != 0.0) v += jb.beta*(double)jb.Cin[(size_t)gm*jb.ldcin + gn];
      jb.Cout[(size_t)gm*jb.ldc + gn] = (float)v;
    }
  }
}

__device__ void run_jobs(const Job* jobs, int njobs, float* stage){
  int cum[5]; int tot = 0;
  for (int j=0;j<njobs;j++){
    cum[j] = tot;
    tot += ((jobs[j].M+63)>>6) * ((jobs[j].N+63)>>6);
  }
  cum[njobs] = tot;
  for (int t = blockIdx.x; t < tot; t += GRID){
    int j = 0;
    while (j+1 < njobs && t >= cum[j+1]) j++;
    run_tile(jobs[j], t - cum[j], stage);
  }
}

// ---------------- Gauss-Jordan, ping-pong, 1 barrier/panel (r17/r18-verified) -------
__device__ void gj_pivinv_lds(const float* A, int lda, int n, int k0,
                              double* TPl, double* ckrk){
  int bs = n - k0; if (bs > 64) bs = 64;
  double* ck = ckrk;
  double* rk = ckrk + 64;
  int tid = threadIdx.x;
  for (int l = tid; l < bs*bs; l += TPB){
    int i=l/bs, j=l-i*bs;
    TPl[i*65+j] = (double)A[(size_t)(k0+i)*lda + k0+j];
  }
  __syncthreads();
  for (int k=0;k<bs;k++){
    double d = 1.0/TPl[k*65+k];
    if (tid < bs){ ck[tid] = TPl[tid*65+k]; rk[tid] = (tid==k) ? d : TPl[k*65+tid]*d; }
    __syncthreads();
    for (int l = tid; l < bs*bs; l += TPB){
      int i=l/bs, j=l-i*bs;
      double v;
      if (i==k) v = rk[j];
      else if (j==k) v = -ck[i]*d;
      else v = TPl[i*65+j] - ck[i]*rk[j];
      TPl[i*65+j] = v;
    }
    __syncthreads();
  }
}

__device__ void gj_phaseB(const float* Ac, float* An, int lda, int n, int k0,
                          const double* TPl, float* Pn, float* stage){
  int bs = n - k0; if (bs > 64) bs = 64;
  int nout = n - bs;
  int ntc = (n+63)>>6, ntm = (nout+63)>>6;
  float* As = stage;          // [16][68]
  float* Bs = stage + 1088;   // [16][68]
  int tid = threadIdx.x, tx = tid%16, ty = tid/16;
  int T = ntm*ntc;
  for (int t = blockIdx.x; t < T; t += GRID){
    int mi = t / ntc, ci = t - mi*ntc;
    int m0 = mi*64, j0 = ci*64;
    double acc[4][4] = {};
    for (int kp=0; kp<bs; kp+=16){
      for (int l=tid; l<1024; l+=TPB){
        int k=l>>6, j=l&63;
        Bs[k*68+j] = (j0+j<n) ? Ac[(size_t)(k0+kp+k)*lda + j0+j] : 0.f;
      }
      __syncthreads();
      #pragma unroll
      for (int kk=0; kk<16; ++kk){
        double a0=(ty*4+0<bs)?TPl[(ty*4+0)*65 + kp+kk]:0.0;
        double a1=(ty*4+1<bs)?TPl[(ty*4+1)*65 + kp+kk]:0.0;
        double a2=(ty*4+2<bs)?TPl[(ty*4+2)*65 + kp+kk]:0.0;
        double a3=(ty*4+3<bs)?TPl[(ty*4+3)*65 + kp+kk]:0.0;
        float4 bv = *(const float4*)&Bs[kk*68 + tx*4];
        double b0=bv.x, b1=bv.y, b2=bv.z, b3=bv.w;
        acc[0][0]+=a0*b0; acc[0][1]+=a0*b1; acc[0][2]+=a0*b2; acc[0][3]+=a0*b3;
        acc[1][0]+=a1*b0; acc[1][1]+=a1*b1; acc[1][2]+=a1*b2; acc[1][3]+=a1*b3;
        acc[2][0]+=a2*b0; acc[2][1]+=a2*b1; acc[2][2]+=a2*b2; acc[2][3]+=a2*b3;
        acc[3][0]+=a3*b0; acc[3][1]+=a3*b1; acc[3][2]+=a3*b2; acc[3][3]+=a3*b3;
      }
      __syncthreads();
    }
    for (int i=0;i<4;i++) for (int j=0;j<4;j++){
      int li = ty*4+i, lj = tx*4+j;
      int gj = j0 + lj;
      if (li < bs){
        double v = acc[i][j];
        if (gj >= k0 && gj < k0+bs) v = TPl[li*65 + (gj-k0)];
        Pn[li*68+lj] = (float)v;
      }
    }
    __syncthreads();
    if (mi == 0){
      for (int l = tid; l < bs*64; l += TPB){
        int i2 = l>>6, j2 = l&63;
        int gj = j0 + j2;
        if (gj < n) An[(size_t)(k0+i2)*lda + gj] = Pn[i2*68+j2];
      }
    }
    double acc2[4][4] = {};
    for (int kp=0; kp<bs; kp+=16){
      for (int l=tid; l<1024; l+=TPB){
        int k=l>>6, m=l&63;
        int gm = m0+m;
        float v = 0.f;
        if (gm < nout){
          int gi = (gm < k0) ? gm : gm + bs;
          v = Ac[(size_t)gi*lda + k0 + kp + k];
        }
        As[k*68+m] = v;
      }
      __syncthreads();
      #pragma unroll
      for (int kk=0; kk<16; ++kk){
        float4 av = *(const float4*)&As[kk*68 + ty*4];
        float4 bv = *(const float4*)&Pn[(kp+kk)*68 + tx*4];
        double a0=av.x, a1=av.y, a2=av.z, a3=av.w;
        double b0=bv.x, b1=bv.y, b2=bv.z, b3=bv.w;
        acc2[0][0]+=a0*b0; acc2[0][1]+=a0*b1; acc2[0][2]+=a0*b2; acc2[0][3]+=a0*b3;
        acc2[1][0]+=a1*b0; acc2[1][1]+=a1*b1; acc2[1][2]+=a1*b2; acc2[1][3]+=a1*b3;
        acc2[2][0]+=a2*b0; acc2[2][1]+=a2*b1; acc2[2][2]+=a2*b2; acc2[2][3]+=a2*b3;
        acc2[3][0]+=a3*b0; acc2[3][1]+=a3*b1; acc2[3][2]+=a3*b2; acc2[3][3]+=a3*b3;
      }
      __syncthreads();
    }
    for (int i=0;i<4;i++) for (int j=0;j<4;j++){
      int gm = m0 + ty*4 + i, gj = j0 + tx*4 + j;
      if (gm < nout && gj < n){
        int gi = (gm < k0) ? gm : gm + bs;
        double base = (gj >= k0 && gj < k0+bs) ? 0.0 : (double)Ac[(size_t)gi*lda + gj];
        An[(size_t)gi*lda + gj] = (float)(base - acc2[i][j]);
      }
    }
    __syncthreads();
  }
}

__device__ float* gj_inv(float* A, float* B, int n, double* TPl, float* Pn,
                         float* stage, double* ckrk, unsigned* cnt, int& bid){
  float* cur = A; float* nxt = B;
  for (int k0 = 0; k0 < n; k0 += 64){
    gj_pivinv_lds(cur, n, n, k0, TPl, ckrk);
    gj_phaseB(cur, nxt, n, n, k0, TPl, Pn, stage);
    gbar(cnt, bid);
    float* tmp = cur; cur = nxt; nxt = tmp;
  }
  return cur;
}

// ---------------- misc stages ----------------
__device__ void st_copy(const float* s, float* d, size_t n){
  for (size_t i = (size_t)blockIdx.x*TPB + threadIdx.x; i < n; i += (size_t)gridDim.x*TPB)
    d[i] = s[i];
}

__device__ void st_out(const float* Bg, float* out){
  int stride = gridDim.x*TPB;
  for (int idx = blockIdx.x*TPB + threadIdx.x; idx < 128*800; idx += stride){
    if (idx < 128*320){
      int t = idx/320, i = idx-(idx/320)*320;
      out[idx] = Bg[(size_t)(480+i)*NBT + t];
    } else {
      int l = idx - 128*320;
      int t = l/480, i = l-(l/480)*480;
      out[idx] = Bg[(size_t)i*NBT + t];
    }
  }
}

__global__ __launch_bounds__(256) void k_init(unsigned* cnt){
  int i = blockIdx.x*256 + threadIdx.x;
  if (i < 1024) cnt[i] = 0;
}

// ---------------- mega kernel ----------------
__global__ __launch_bounds__(256) void k_mega(
    const float* Up, const float* Yp, const float* Uf, const float* Yf,
    const float* q, const float* r, const float* lam,
    const float* yref, const float* uref, const float* u_ini, const float* y_ini,
    float* out,
    float* Gram, float* M11, float* T12, float* G1, float* SP, float* R1,
    float* U1, float* X2b, float* Sm, float* dM, float* rhs2, float* tAc,
    float* P1, float* BUZ, float* EXT, unsigned* cnt){
  // LDS map (doubles), all float4 bases 16B-aligned (r18-verified):
  //   TPl  f64[64][65]              : 0    .. 4160
  //   Pn   f32[64][68] = 4352 f     : 4160 .. 6336
  //   stage f32 2x[16][68] = 2176 f : 6336 .. 7424
  //   ckrk f64[128]                 : 7424 .. 7552
  // st_gram reuses shd front as f32 2x[32][68] = 4352 f = 2176 d.
  __shared__ double shd[7552];
  double* TPl  = shd;
  float*  Pn   = (float*)(shd + 4160);
  float*  stage= (float*)(shd + 6336);
  double* ckrk = shd + 7424;
  int bid = 0;
  double sg = 2.0*(double)lam[0];
  double isg = 1.0/sg, isg2 = isg*isg;

  st_gram(Yf, Uf, Up, Yp, Gram, (float*)shd);
  gbar(cnt, bid);
  st_assemble(Gram, q, r, isg, yref, uref, u_ini, y_ini, EXT, T12, R1, dM, rhs2);
  gbar(cnt, bid);
  { // {3,14,17} flattened
    Job js[3] = {
      {Gram, dM, R1+NC, R1+NC, NQ, NBT, NRHS, NRHS, KU, NBT, KB, 0, 1, 1.0, 0.0},
      {Gram+(size_t)800*NQ, dM, rhs2, tAc, NQ, NBT, NBT, NBT, NC, NBT, KB, 0, 0, isg, 1.0},
      {Gram, dM, P1, P1, NQ, NBT, NBT, NBT, KB, NBT, KB, 0, 0, isg, 0.0},
    };
    run_jobs(js, 3, stage);
  }
  gbar(cnt, bid);
  float* M11f = gj_inv(EXT, M11, KB, TPl, Pn, stage, ckrk, cnt, bid);   // 13 barriers
  { // {5,8}
    Job js[2] = {
      {M11f, T12, G1, G1, KB, KP, KP, KP, KB, KP, KB, 0, 0, 1.0, 0.0},
      {M11f, R1, U1, U1, KB, NRHS, NRHS, NRHS, KB, NRHS, KB, 0, 0, 1.0, 0.0},
    };
    run_jobs(js, 2, stage);
  }
  gbar(cnt, bid);
  { // {6,9}
    Job js[2] = {
      {T12, G1, SP, SP, KP, KP, KP, KP, KP, KP, KB, 1, 0, 1.0, 0.0},
      {T12, U1, R1+(size_t)KB*NRHS, R1+(size_t)KB*NRHS, KP, NRHS, NRHS, NRHS, KP, NRHS, KB, 1, 0, 1.0, -1.0},
    };
    run_jobs(js, 2, stage);
  }
  gbar(cnt, bid);
  float* SPf = gj_inv(SP, EXT, KP, TPl, Pn, stage, ckrk, cnt, bid);     // 12 barriers
  { // X2 = SPi @ V
    Job js[1] = {
      {SPf, R1+(size_t)KB*NRHS, X2b, X2b, KP, NRHS, NRHS, NRHS, KP, NRHS, KP, 0, 0, 1.0, 0.0},
    };
    run_jobs(js, 1, stage);
  }
  gbar(cnt, bid);
  { // {11}: copy X2 -> R1low (disjoint rows) + X1 = U1 - G1 @ X2
    st_copy(X2b, R1+(size_t)KB*NRHS, (size_t)KP*NRHS);
    Job js[1] = {
      {G1, X2b, U1, R1, KP, NRHS, NRHS, NRHS, KB, NRHS, KP, 0, 0, -1.0, 1.0},
    };
    run_jobs(js, 1, stage);
  }
  gbar(cnt, bid);
  { // {12,15,19,20} flattened
    Job js[4] = {
      {Gram+800, R1, Gram+(size_t)800*NQ+800, EXT, NQ, NRHS, NQ, NC, NC, NC, KU, 1, 1, -isg2, isg},
      {Gram+800, R1+NC, tAc, rhs2, NQ, NRHS, NBT, NBT, NC, NBT, KU, 1, 1, -isg2, 1.0},
      {Gram, R1+NC, P1, P1, NQ, NRHS, NBT, NBT, KB, NBT, KU, 1, 1, -isg2, 1.0},
      {Gram, R1, BUZ, BUZ, NQ, NRHS, NC, NC, KB, NC, KU, 1, 1, 1.0, 0.0},
    };
    run_jobs(js, 4, stage);
  }
  gbar(cnt, bid);
  float* Smf = gj_inv(EXT, Sm, NC, TPl, Pn, stage, ckrk, cnt, bid);     // 7 barriers
  { // nu = Smi @ rhs2 -> tAc
    Job js[1] = {
      {Smf, rhs2, tAc, tAc, NC, NBT, NBT, NBT, NC, NBT, NC, 0, 0, 1.0, 0.0},
    };
    run_jobs(js, 1, stage);
  }
  gbar(cnt, bid);
  { // {18}: P1 -= isg*(BA^T nu)
    Job js[1] = {
      {Gram+800, tAc, P1, P1, NQ, NBT, NBT, NBT, KB, NBT, NC, 0, 0, -isg, 1.0},
    };
    run_jobs(js, 1, stage);
  }
  gbar(cnt, bid);
  { // {21}: P1 += isg2*(BUZ nu)
    Job js[1] = {
      {BUZ, tAc, P1, P1, NC, NBT, NBT, NBT, KB, NBT, NC, 0, 0, isg2, 1.0},
    };
    run_jobs(js, 1, stage);
  }
  gbar(cnt, bid);
  st_out(P1, out);
}

extern "C" void kernel_launch(void* const* d_in, const int* in_sizes, int n_in,
                              void* d_out, int out_size, void* d_ws, size_t ws_size,
                              hipStream_t stream){
  const float* Up   = (const float*)d_in[0];
  const float* Yp   = (const float*)d_in[1];
  const float* Uf   = (const float*)d_in[2];
  const float* Yf   = (const float*)d_in[3];
  // d_in[4] = IPI : unused (projector handled analytically)
  const float* q    = (const float*)d_in[5];
  const float* r    = (const float*)d_in[6];
  const float* lam  = (const float*)d_in[7];
  const float* yref = (const float*)d_in[8];
  const float* uref = (const float*)d_in[9];
  const float* u_ini= (const float*)d_in[10];
  const float* y_ini= (const float*)d_in[11];
  float* out = (float*)d_out;

  float* W = (float*)d_ws;
  size_t o = 0;
  float* Gram = W + o; o += (size_t)NQ*NQ;
  float* M11  = W + o; o += (size_t)KB*KB;
  float* T12  = W + o; o += (size_t)KB*KP;
  float* G1   = W + o; o += (size_t)KB*KP;
  float* SP   = W + o; o += (size_t)KP*KP;
  float* R1   = W + o; o += (size_t)KU*NRHS;
  float* U1   = W + o; o += (size_t)KB*NRHS;
  float* X2b  = W + o; o += (size_t)KP*NRHS;
  float* Sm   = W + o; o += (size_t)NC*NC;
  float* dM   = W + o; o += (size_t)KB*NBT;
  float* rhs2 = W + o; o += (size_t)NC*NBT;
  float* tAc  = W + o; o += (size_t)NC*NBT;
  float* P1   = W + o; o += (size_t)KB*NBT;
  float* BUZ  = W + o; o += (size_t)KB*NC;
  float* EXT  = W + o; o += (size_t)KB*KB;
  unsigned* cnt = (unsigned*)(W + o); o += 512;
  if (ws_size < o*sizeof(float)) return;

  k_init<<<4,256,0,stream>>>(cnt);
  k_mega<<<GRID,TPB,0,stream>>>(Up,Yp,Uf,Yf,q,r,lam,yref,uref,u_ini,y_ini,out,
      Gram,M11,T12,G1,SP,R1,U1,X2b,Sm,dM,rhs2,tAc,P1,BUZ,EXT,cnt);
}

// Round 22
// 5795.699 us; speedup vs baseline: 1.6269x; 1.5354x over previous
//
#include <hip/hip_runtime.h>
#include <math.h>

#define NDIMX 2941
#define NQ 1200
#define KB 800
#define KP 720
#define KU 1520
#define NC 400
#define NBT 128
#define NRHS 528
#define GRID 256
#define TPB 512

__device__ __forceinline__ int umap(int x){ return (x < 1200) ? x : x - 720; }

__device__ __forceinline__ const float* qrowp(int rr, const float* Yf, const float* Uf,
                                              const float* Up, const float* Yp){
  if (rr < 480) return Yf + (size_t)rr*NDIMX;
  if (rr < 800) return Uf + (size_t)(rr-480)*NDIMX;
  if (rr < 960) return Up + (size_t)(rr-800)*NDIMX;
  return Yp + (size_t)(rr-960)*NDIMX;
}

// ---------------- device-scope grid barrier (round-5/9 verified protocol) ----------------
__device__ __forceinline__ void gbar(unsigned* cnt, int& id){
  __syncthreads();
  if (threadIdx.x == 0){
    unsigned* c = cnt + id;
    __hip_atomic_fetch_add(c, 1u, __ATOMIC_RELEASE, __HIP_MEMORY_SCOPE_SYSTEM);
    while (__hip_atomic_load(c, __ATOMIC_RELAXED, __HIP_MEMORY_SCOPE_SYSTEM) < (unsigned)GRID){
      __builtin_amdgcn_s_sleep(8);
    }
    (void)__hip_atomic_load(c, __ATOMIC_ACQUIRE, __HIP_MEMORY_SCOPE_AGENT);
  }
  __syncthreads();
  id++;
}

// XCD-aware bijective tile range (m204) — Gram only
__device__ __forceinline__ void swz(int T, int& t0, int& tend){
  int x = blockIdx.x & 7, y = blockIdx.x >> 3;
  int q = T >> 3, r = T & 7;
  int nx = q + (x < r ? 1 : 0);
  int base = (x < r) ? x*(q+1) : r*(q+1) + (x-r)*q;
  t0 = base + y; tend = base + nx;
}

// ---------------- Gram stage (f32; 2x4 per thread, 512 threads) ----------------
__device__ void st_gram(const float* Yf, const float* Uf, const float* Up, const float* Yp,
                        float* G, float* shf){
  float* At = shf;            // [32][68]
  float* Bt = shf + 32*68;    // [32][68]
  const int ntri = 190;
  int tid = threadIdx.x, tx = tid%16, ty = tid/16;   // ty in [0,32)
  int t0, tend; swz(ntri, t0, tend);
  for (int t = t0; t < tend; t += 32){
    int rem = t, ti = 0;
    while (rem >= ti+1){ rem -= ti+1; ++ti; }
    int tj = rem;
    int i0 = ti*64, j0 = tj*64;
    float acc[2][4] = {};
    for (int k0 = 0; k0 < NDIMX; k0 += 32){
      for (int l = tid; l < 2048; l += TPB){
        int r2 = l >> 5, k = l & 31;
        int gr = i0 + r2, gk = k0 + k;
        At[k*68 + r2] = (gr < NQ && gk < NDIMX) ? qrowp(gr,Yf,Uf,Up,Yp)[gk] : 0.f;
      }
      if (ti != tj){
        for (int l = tid; l < 2048; l += TPB){
          int r2 = l >> 5, k = l & 31;
          int gr = j0 + r2, gk = k0 + k;
          Bt[k*68 + r2] = (gr < NQ && gk < NDIMX) ? qrowp(gr,Yf,Uf,Up,Yp)[gk] : 0.f;
        }
      }
      __syncthreads();
      float* Bp = (ti==tj) ? At : Bt;
      #pragma unroll 8
      for (int kk=0; kk<32; ++kk){
        float2 av = *(const float2*)&At[kk*68 + ty*2];
        float4 bv = *(const float4*)&Bp[kk*68 + tx*4];
        float a0=av.x,a1=av.y;
        float b0=bv.x,b1=bv.y,b2=bv.z,b3=bv.w;
        acc[0][0]+=a0*b0; acc[0][1]+=a0*b1; acc[0][2]+=a0*b2; acc[0][3]+=a0*b3;
        acc[1][0]+=a1*b0; acc[1][1]+=a1*b1; acc[1][2]+=a1*b2; acc[1][3]+=a1*b3;
      }
      __syncthreads();
    }
    for (int i=0;i<2;i++) for (int j=0;j<4;j++){
      int gi = i0 + ty*2 + i, gj = j0 + tx*4 + j;
      if (gi < NQ && gj < NQ){
        G[(size_t)gi*NQ+gj] = acc[i][j];
        G[(size_t)gj*NQ+gi] = acc[i][j];
      }
    }
  }
}

// ---------------- fused elementwise assembly (r17-verified; TPB-generic) ----------------
__device__ void st_assemble(const float* G, const float* q, const float* r, double isg,
    const float* yref, const float* uref, const float* u_ini, const float* y_ini,
    float* M11, float* T12, float* R1, float* dM, float* rhs2){
  int tid0 = blockIdx.x*TPB + threadIdx.x, stride = gridDim.x*TPB;
  for (int idx=tid0; idx<KB*KB; idx+=stride){
    int i=idx/KB, j=idx-i*KB;
    double v = (double)G[(size_t)i*NQ+j]*isg;
    if (i==j){ double w=(i<480)?(double)q[i%12]:(double)r[(i-480)%8]; v += 0.5/w; }
    M11[idx]=(float)v;
  }
  for (int idx=tid0; idx<KB*KP; idx+=stride){
    int i=idx/KP, j=idx-i*KP;
    int pc=(j<400)?(800+j):(80+j);
    T12[idx]=(float)((double)G[(size_t)i*NQ+pc]*isg);
  }
  for (int idx=tid0; idx<KU*NC; idx+=stride){
    int i=idx/NC, j=idx-i*NC;
    R1[(size_t)i*NRHS+j]=G[(size_t)umap(i)*NQ+800+j];
  }
  for (int idx=tid0; idx<KB*NBT; idx+=stride){
    int k=idx/NBT, t=idx-k*NBT;
    double v=(k<480)? 2.0*(double)q[k%12]*(double)yref[(size_t)t*480+k]
                    : 2.0*(double)r[(k-480)%8]*(double)uref[(size_t)t*320+(k-480)];
    dM[idx]=(float)v;
  }
  for (int idx=tid0; idx<NC*NBT; idx+=stride){
    int j=idx/NBT, t=idx-j*NBT;
    rhs2[idx]= -((j<160)?u_ini[(size_t)t*160+j]:y_ini[(size_t)t*240+(j-160)]);
  }
}

// ---------------- multi-GEMM job executor (512 threads, 2x4/thread) --------
struct Job {
  const float* A; const float* B; const float* Cin; float* Cout;
  int lda, ldb, ldcin, ldc, M, N, K, transa, mapa;
  double alpha, beta;
};

__device__ void run_tile(const Job& jb, int t, float* stage){
  float* As = stage;          // [16][68]
  float* Bs = stage + 1088;   // [16][68]
  int tid = threadIdx.x, tx = tid%16, ty = tid/16;   // ty in [0,32)
  const float* A = jb.A; const float* B = jb.B;
  int lda = jb.lda, ldb = jb.ldb, M = jb.M, N = jb.N, K = jb.K;
  int transa = jb.transa, mapa = jb.mapa;
  int ntn = (N+63)>>6;
  int m0 = (t/ntn)*64, n0 = (t - (t/ntn)*ntn)*64;
  double acc[2][4] = {};
  float ra[2], rb[2];
  auto loadAB = [&](int k0v){
    #pragma unroll
    for (int s=0;s<2;s++){
      int l = tid + s*TPB;
      float v = 0.f;
      if (transa == 0){
        int m = l>>4, k = l&15;
        int gm = m0+m, gk = k0v+k;
        if (gm<M && gk<K){ int row = mapa ? umap(gm) : gm; v = A[(size_t)row*lda + gk]; }
      } else {
        int k = l>>6, m = l&63;
        int gm = m0+m, gk = k0v+k;
        if (gm<M && gk<K){ int row = mapa ? umap(gk) : gk; v = A[(size_t)row*lda + gm]; }
      }
      ra[s] = v;
      int kb = l>>6, n = l&63;
      int gn = n0+n, gkb = k0v+kb;
      rb[s] = (gn<N && gkb<K) ? B[(size_t)gkb*ldb + gn] : 0.f;
    }
  };
  loadAB(0);
  for (int k0 = 0; k0 < K; k0 += 16){
    __syncthreads();
    #pragma unroll
    for (int s=0;s<2;s++){
      int l = tid + s*TPB;
      if (transa == 0){ int m=l>>4, k=l&15; As[k*68+m] = ra[s]; }
      else            { int k=l>>6, m=l&63; As[k*68+m] = ra[s]; }
      int kb=l>>6, n=l&63; Bs[kb*68+n] = rb[s];
    }
    __syncthreads();
    if (k0+16 < K) loadAB(k0+16);
    #pragma unroll
    for (int kk=0; kk<16; ++kk){
      float2 av = *(const float2*)&As[kk*68 + ty*2];
      float4 bv = *(const float4*)&Bs[kk*68 + tx*4];
      double a0=av.x, a1=av.y;
      double b0=bv.x, b1=bv.y, b2=bv.z, b3=bv.w;
      acc[0][0]+=a0*b0; acc[0][1]+=a0*b1; acc[0][2]+=a0*b2; acc[0][3]+=a0*b3;
      acc[1][0]+=a1*b0; acc[1][1]+=a1*b1; acc[1][2]+=a1*b2; acc[1][3]+=a1*b3;
    }
    __syncthreads();
  }
  for (int i=0;i<2;i++) for (int j=0;j<4;j++){
    int gm = m0 + ty*2 + i, gn = n0 + tx*4 + j;
    if (gm < M && gn < N){
      double v = jb.alpha*acc[i][j];
      if (jb.beta != 0.0) v += jb.beta*(double)jb.Cin[(size_t)gm*jb.ldcin + gn];
      jb.Cout[(size_t)gm*jb.ldc + gn] = (float)v;
    }
  }
}

__device__ void run_jobs(const Job* jobs, int njobs, float* stage){
  int cum[5]; int tot = 0;
  for (int j=0;j<njobs;j++){
    cum[j] = tot;
    tot += ((jobs[j].M+63)>>6) * ((jobs[j].N+63)>>6);
  }
  cum[njobs] = tot;
  for (int t = blockIdx.x; t < tot; t += GRID){
    int j = 0;
    while (j+1 < njobs && t >= cum[j+1]) j++;
    run_tile(jobs[j], t - cum[j], stage);
  }
}

// ---------------- Gauss-Jordan, ping-pong, 1 barrier/panel (r17/r18-verified math) -------
__device__ void gj_pivinv_lds(const float* A, int lda, int n, int k0,
                              double* TPl, double* ckrk){
  int bs = n - k0; if (bs > 64) bs = 64;
  double* ck = ckrk;
  double* rk = ckrk + 64;
  int tid = threadIdx.x;
  for (int l = tid; l < bs*bs; l += TPB){
    int i=l/bs, j=l-i*bs;
    TPl[i*65+j] = (double)A[(size_t)(k0+i)*lda + k0+j];
  }
  __syncthreads();
  for (int k=0;k<bs;k++){
    double d = 1.0/TPl[k*65+k];
    if (tid < bs){ ck[tid] = TPl[tid*65+k]; rk[tid] = (tid==k) ? d : TPl[k*65+tid]*d; }
    __syncthreads();
    for (int l = tid; l < bs*bs; l += TPB){
      int i=l/bs, j=l-i*bs;
      double v;
      if (i==k) v = rk[j];
      else if (j==k) v = -ck[i]*d;
      else v = TPl[i*65+j] - ck[i]*rk[j];
      TPl[i*65+j] = v;
    }
    __syncthreads();
  }
}

__device__ void gj_phaseB(const float* Ac, float* An, int lda, int n, int k0,
                          const double* TPl, float* Pn, float* stage){
  int bs = n - k0; if (bs > 64) bs = 64;
  int nout = n - bs;
  int ntc = (n+63)>>6, ntm = (nout+63)>>6;
  float* As = stage;          // [16][68]
  float* Bs = stage + 1088;   // [16][68]
  int tid = threadIdx.x, tx = tid%16, ty = tid/16;   // ty in [0,32)
  int T = ntm*ntc;
  for (int t = blockIdx.x; t < T; t += GRID){
    int mi = t / ntc, ci = t - mi*ntc;
    int m0 = mi*64, j0 = ci*64;
    double acc[2][4] = {};
    for (int kp=0; kp<bs; kp+=16){
      for (int l=tid; l<1024; l+=TPB){
        int k=l>>6, j=l&63;
        Bs[k*68+j] = (j0+j<n) ? Ac[(size_t)(k0+kp+k)*lda + j0+j] : 0.f;
      }
      __syncthreads();
      #pragma unroll
      for (int kk=0; kk<16; ++kk){
        double a0=(ty*2+0<bs)?TPl[(ty*2+0)*65 + kp+kk]:0.0;
        double a1=(ty*2+1<bs)?TPl[(ty*2+1)*65 + kp+kk]:0.0;
        float4 bv = *(const float4*)&Bs[kk*68 + tx*4];
        double b0=bv.x, b1=bv.y, b2=bv.z, b3=bv.w;
        acc[0][0]+=a0*b0; acc[0][1]+=a0*b1; acc[0][2]+=a0*b2; acc[0][3]+=a0*b3;
        acc[1][0]+=a1*b0; acc[1][1]+=a1*b1; acc[1][2]+=a1*b2; acc[1][3]+=a1*b3;
      }
      __syncthreads();
    }
    for (int i=0;i<2;i++) for (int j=0;j<4;j++){
      int li = ty*2+i, lj = tx*4+j;
      int gj = j0 + lj;
      if (li < bs){
        double v = acc[i][j];
        if (gj >= k0 && gj < k0+bs) v = TPl[li*65 + (gj-k0)];
        Pn[li*68+lj] = (float)v;
      }
    }
    __syncthreads();
    if (mi == 0){
      for (int l = tid; l < bs*64; l += TPB){
        int i2 = l>>6, j2 = l&63;
        int gj = j0 + j2;
        if (gj < n) An[(size_t)(k0+i2)*lda + gj] = Pn[i2*68+j2];
      }
    }
    double acc2[2][4] = {};
    for (int kp=0; kp<bs; kp+=16){
      for (int l=tid; l<1024; l+=TPB){
        int k=l>>6, m=l&63;
        int gm = m0+m;
        float v = 0.f;
        if (gm < nout){
          int gi = (gm < k0) ? gm : gm + bs;
          v = Ac[(size_t)gi*lda + k0 + kp + k];
        }
        As[k*68+m] = v;
      }
      __syncthreads();
      #pragma unroll
      for (int kk=0; kk<16; ++kk){
        float2 av = *(const float2*)&As[kk*68 + ty*2];
        float4 bv = *(const float4*)&Pn[(kp+kk)*68 + tx*4];
        double a0=av.x, a1=av.y;
        double b0=bv.x, b1=bv.y, b2=bv.z, b3=bv.w;
        acc2[0][0]+=a0*b0; acc2[0][1]+=a0*b1; acc2[0][2]+=a0*b2; acc2[0][3]+=a0*b3;
        acc2[1][0]+=a1*b0; acc2[1][1]+=a1*b1; acc2[1][2]+=a1*b2; acc2[1][3]+=a1*b3;
      }
      __syncthreads();
    }
    for (int i=0;i<2;i++) for (int j=0;j<4;j++){
      int gm = m0 + ty*2 + i, gj = j0 + tx*4 + j;
      if (gm < nout && gj < n){
        int gi = (gm < k0) ? gm : gm + bs;
        double base = (gj >= k0 && gj < k0+bs) ? 0.0 : (double)Ac[(size_t)gi*lda + gj];
        An[(size_t)gi*lda + gj] = (float)(base - acc2[i][j]);
      }
    }
    __syncthreads();
  }
}

__device__ float* gj_inv(float* A, float* B, int n, double* TPl, float* Pn,
                         float* stage, double* ckrk, unsigned* cnt, int& bid){
  float* cur = A; float* nxt = B;
  for (int k0 = 0; k0 < n; k0 += 64){
    gj_pivinv_lds(cur, n, n, k0, TPl, ckrk);
    gj_phaseB(cur, nxt, n, n, k0, TPl, Pn, stage);
    gbar(cnt, bid);
    float* tmp = cur; cur = nxt; nxt = tmp;
  }
  return cur;
}

// ---------------- misc stages ----------------
__device__ void st_copy(const float* s, float* d, size_t n){
  for (size_t i = (size_t)blockIdx.x*TPB + threadIdx.x; i < n; i += (size_t)gridDim.x*TPB)
    d[i] = s[i];
}

__device__ void st_out(const float* Bg, float* out){
  int stride = gridDim.x*TPB;
  for (int idx = blockIdx.x*TPB + threadIdx.x; idx < 128*800; idx += stride){
    if (idx < 128*320){
      int t = idx/320, i = idx-(idx/320)*320;
      out[idx] = Bg[(size_t)(480+i)*NBT + t];
    } else {
      int l = idx - 128*320;
      int t = l/480, i = l-(l/480)*480;
      out[idx] = Bg[(size_t)i*NBT + t];
    }
  }
}

__global__ __launch_bounds__(256) void k_init(unsigned* cnt){
  int i = blockIdx.x*256 + threadIdx.x;
  if (i < 1024) cnt[i] = 0;
}

// ---------------- mega kernel ----------------
__global__ __launch_bounds__(TPB) void k_mega(
    const float* Up, const float* Yp, const float* Uf, const float* Yf,
    const float* q, const float* r, const float* lam,
    const float* yref, const float* uref, const float* u_ini, const float* y_ini,
    float* out,
    float* Gram, float* M11, float* T12, float* G1, float* SP, float* R1,
    float* U1, float* X2b, float* Sm, float* dM, float* rhs2, float* tAc,
    float* P1, float* BUZ, float* EXT, unsigned* cnt){
  // LDS map (doubles), all float4 bases 16B-aligned (r18-verified):
  //   TPl  f64[64][65]              : 0    .. 4160
  //   Pn   f32[64][68] = 4352 f     : 4160 .. 6336
  //   stage f32 2x[16][68] = 2176 f : 6336 .. 7424
  //   ckrk f64[128]                 : 7424 .. 7552
  // st_gram reuses shd front as f32 2x[32][68] = 4352 f = 2176 d.
  __shared__ double shd[7552];
  double* TPl  = shd;
  float*  Pn   = (float*)(shd + 4160);
  float*  stage= (float*)(shd + 6336);
  double* ckrk = shd + 7424;
  int bid = 0;
  double sg = 2.0*(double)lam[0];
  double isg = 1.0/sg, isg2 = isg*isg;

  st_gram(Yf, Uf, Up, Yp, Gram, (float*)shd);
  gbar(cnt, bid);
  st_assemble(Gram, q, r, isg, yref, uref, u_ini, y_ini, EXT, T12, R1, dM, rhs2);
  gbar(cnt, bid);
  { // {3,14,17} flattened
    Job js[3] = {
      {Gram, dM, R1+NC, R1+NC, NQ, NBT, NRHS, NRHS, KU, NBT, KB, 0, 1, 1.0, 0.0},
      {Gram+(size_t)800*NQ, dM, rhs2, tAc, NQ, NBT, NBT, NBT, NC, NBT, KB, 0, 0, isg, 1.0},
      {Gram, dM, P1, P1, NQ, NBT, NBT, NBT, KB, NBT, KB, 0, 0, isg, 0.0},
    };
    run_jobs(js, 3, stage);
  }
  gbar(cnt, bid);
  float* M11f = gj_inv(EXT, M11, KB, TPl, Pn, stage, ckrk, cnt, bid);   // 13 barriers
  { // {5,8}
    Job js[2] = {
      {M11f, T12, G1, G1, KB, KP, KP, KP, KB, KP, KB, 0, 0, 1.0, 0.0},
      {M11f, R1, U1, U1, KB, NRHS, NRHS, NRHS, KB, NRHS, KB, 0, 0, 1.0, 0.0},
    };
    run_jobs(js, 2, stage);
  }
  gbar(cnt, bid);
  { // {6,9}
    Job js[2] = {
      {T12, G1, SP, SP, KP, KP, KP, KP, KP, KP, KB, 1, 0, 1.0, 0.0},
      {T12, U1, R1+(size_t)KB*NRHS, R1+(size_t)KB*NRHS, KP, NRHS, NRHS, NRHS, KP, NRHS, KB, 1, 0, 1.0, -1.0},
    };
    run_jobs(js, 2, stage);
  }
  gbar(cnt, bid);
  float* SPf = gj_inv(SP, EXT, KP, TPl, Pn, stage, ckrk, cnt, bid);     // 12 barriers
  { // X2 = SPi @ V
    Job js[1] = {
      {SPf, R1+(size_t)KB*NRHS, X2b, X2b, KP, NRHS, NRHS, NRHS, KP, NRHS, KP, 0, 0, 1.0, 0.0},
    };
    run_jobs(js, 1, stage);
  }
  gbar(cnt, bid);
  { // {11}: copy X2 -> R1low (disjoint rows) + X1 = U1 - G1 @ X2
    st_copy(X2b, R1+(size_t)KB*NRHS, (size_t)KP*NRHS);
    Job js[1] = {
      {G1, X2b, U1, R1, KP, NRHS, NRHS, NRHS, KB, NRHS, KP, 0, 0, -1.0, 1.0},
    };
    run_jobs(js, 1, stage);
  }
  gbar(cnt, bid);
  { // {12,15,19,20} flattened
    Job js[4] = {
      {Gram+800, R1, Gram+(size_t)800*NQ+800, EXT, NQ, NRHS, NQ, NC, NC, NC, KU, 1, 1, -isg2, isg},
      {Gram+800, R1+NC, tAc, rhs2, NQ, NRHS, NBT, NBT, NC, NBT, KU, 1, 1, -isg2, 1.0},
      {Gram, R1+NC, P1, P1, NQ, NRHS, NBT, NBT, KB, NBT, KU, 1, 1, -isg2, 1.0},
      {Gram, R1, BUZ, BUZ, NQ, NRHS, NC, NC, KB, NC, KU, 1, 1, 1.0, 0.0},
    };
    run_jobs(js, 4, stage);
  }
  gbar(cnt, bid);
  float* Smf = gj_inv(EXT, Sm, NC, TPl, Pn, stage, ckrk, cnt, bid);     // 7 barriers
  { // nu = Smi @ rhs2 -> tAc
    Job js[1] = {
      {Smf, rhs2, tAc, tAc, NC, NBT, NBT, NBT, NC, NBT, NC, 0, 0, 1.0, 0.0},
    };
    run_jobs(js, 1, stage);
  }
  gbar(cnt, bid);
  { // {18}: P1 -= isg*(BA^T nu)
    Job js[1] = {
      {Gram+800, tAc, P1, P1, NQ, NBT, NBT, NBT, KB, NBT, NC, 0, 0, -isg, 1.0},
    };
    run_jobs(js, 1, stage);
  }
  gbar(cnt, bid);
  { // {21}: P1 += isg2*(BUZ nu)
    Job js[1] = {
      {BUZ, tAc, P1, P1, NC, NBT, NBT, NBT, KB, NBT, NC, 0, 0, isg2, 1.0},
    };
    run_jobs(js, 1, stage);
  }
  gbar(cnt, bid);
  st_out(P1, out);
}

extern "C" void kernel_launch(void* const* d_in, const int* in_sizes, int n_in,
                              void* d_out, int out_size, void* d_ws, size_t ws_size,
                              hipStream_t stream){
  const float* Up   = (const float*)d_in[0];
  const float* Yp   = (const float*)d_in[1];
  const float* Uf   = (const float*)d_in[2];
  const float* Yf   = (const float*)d_in[3];
  // d_in[4] = IPI : unused (projector handled analytically)
  const float* q    = (const float*)d_in[5];
  const float* r    = (const float*)d_in[6];
  const float* lam  = (const float*)d_in[7];
  const float* yref = (const float*)d_in[8];
  const float* uref = (const float*)d_in[9];
  const float* u_ini= (const float*)d_in[10];
  const float* y_ini= (const float*)d_in[11];
  float* out = (float*)d_out;

  float* W = (float*)d_ws;
  size_t o = 0;
  float* Gram = W + o; o += (size_t)NQ*NQ;
  float* M11  = W + o; o += (size_t)KB*KB;
  float* T12  = W + o; o += (size_t)KB*KP;
  float* G1   = W + o; o += (size_t)KB*KP;
  float* SP   = W + o; o += (size_t)KP*KP;
  float* R1   = W + o; o += (size_t)KU*NRHS;
  float* U1   = W + o; o += (size_t)KB*NRHS;
  float* X2b  = W + o; o += (size_t)KP*NRHS;
  float* Sm   = W + o; o += (size_t)NC*NC;
  float* dM   = W + o; o += (size_t)KB*NBT;
  float* rhs2 = W + o; o += (size_t)NC*NBT;
  float* tAc  = W + o; o += (size_t)NC*NBT;
  float* P1   = W + o; o += (size_t)KB*NBT;
  float* BUZ  = W + o; o += (size_t)KB*NC;
  float* EXT  = W + o; o += (size_t)KB*KB;
  unsigned* cnt = (unsigned*)(W + o); o += 512;
  if (ws_size < o*sizeof(float)) return;

  k_init<<<4,256,0,stream>>>(cnt);
  k_mega<<<GRID,TPB,0,stream>>>(Up,Yp,Uf,Yf,q,r,lam,yref,uref,u_ini,y_ini,out,
      Gram,M11,T12,G1,SP,R1,U1,X2b,Sm,dM,rhs2,tAc,P1,BUZ,EXT,cnt);
}